// Round 1
// baseline (73.886 us; speedup 1.0000x reference)
//
#include <hip/hip_runtime.h>
#include <hip/hip_bf16.h>

typedef __attribute__((ext_vector_type(8))) short short8;
typedef __attribute__((ext_vector_type(4))) short short4b;
typedef __attribute__((ext_vector_type(4))) float f32x4;

#define NBATCH 32
#define NT 512
#define NS 512
#define ND 1024
#define BM 128
#define BN 128
#define BK 64
#define NKSTEP (ND / BK) /* 16 */

__device__ __forceinline__ short f2bf(float f) {
    union { __hip_bfloat16 h; short s; } u;
    u.h = __float2bfloat16(f);
    return u.s;
}

// 128x128 output tile per block, 4 waves (2x2), each wave 64x64 via 4x4
// fragments of v_mfma_f32_16x16x32_bf16. f32 inputs are reg-staged, converted
// to bf16, and written to XOR-swizzled LDS; row sum-of-squares (for the
// cosine denominator) is accumulated in f32 during staging (each element of
// the tile is loaded exactly once per block -> norms are free).
__global__ __launch_bounds__(256, 2)
void paircos_mfma(const float* __restrict__ sup, const float* __restrict__ tgt,
                  float* __restrict__ out) {
    __shared__ __align__(16) short As[BM * BK]; // targets tile (M rows)
    __shared__ __align__(16) short Bs[BN * BK]; // supports tile (N rows)
    __shared__ float tn[BM];
    __shared__ float sn[BN];

    const int tid = threadIdx.x;
    const int b   = blockIdx.y;
    const int bt0 = (blockIdx.x >> 2) * BM;
    const int bs0 = (blockIdx.x & 3)  * BN;

    // staging decomposition: thread covers rows {j*16+g : j=0..7}, float4-col c
    const int g = tid >> 4;  // 0..15
    const int c = tid & 15;  // 0..15

    const float* tb = tgt + (size_t)b * NT * ND + (size_t)(bt0 + g) * ND + c * 4;
    const float* sb = sup + (size_t)b * NS * ND + (size_t)(bs0 + g) * ND + c * 4;

    const int wave = tid >> 6;
    const int lane = tid & 63;
    const int wr = (wave >> 1) * 64;
    const int wc = (wave & 1) * 64;
    const int lhi = lane >> 4;  // 0..3 (k-group)
    const int llo = lane & 15;  // row/col within fragment

    f32x4 acc[4][4];
#pragma unroll
    for (int m = 0; m < 4; ++m)
#pragma unroll
        for (int n = 0; n < 4; ++n)
            acc[m][n] = (f32x4){0.f, 0.f, 0.f, 0.f};

    float sqA[8], sqB[8];
#pragma unroll
    for (int j = 0; j < 8; ++j) { sqA[j] = 0.f; sqB[j] = 0.f; }

    float4 rA[8], rB[8];
#pragma unroll
    for (int j = 0; j < 8; ++j) {
        rA[j] = *reinterpret_cast<const float4*>(tb + (size_t)j * 16 * ND);
        rB[j] = *reinterpret_cast<const float4*>(sb + (size_t)j * 16 * ND);
    }

    for (int kk = 0; kk < NKSTEP; ++kk) {
        __syncthreads(); // previous tile's consumers done
#pragma unroll
        for (int j = 0; j < 8; ++j) {
            const int row = j * 16 + g;
            const int off = row * BK + ((c * 4) ^ ((row & 7) << 3));
            float4 a = rA[j];
            sqA[j] = fmaf(a.x, a.x, fmaf(a.y, a.y, fmaf(a.z, a.z, fmaf(a.w, a.w, sqA[j]))));
            short4b va = { f2bf(a.x), f2bf(a.y), f2bf(a.z), f2bf(a.w) };
            *reinterpret_cast<short4b*>(&As[off]) = va;
            float4 bb = rB[j];
            sqB[j] = fmaf(bb.x, bb.x, fmaf(bb.y, bb.y, fmaf(bb.z, bb.z, fmaf(bb.w, bb.w, sqB[j]))));
            short4b vb = { f2bf(bb.x), f2bf(bb.y), f2bf(bb.z), f2bf(bb.w) };
            *reinterpret_cast<short4b*>(&Bs[off]) = vb;
        }
        __syncthreads(); // tile kk visible

        if (kk + 1 < NKSTEP) { // prefetch next K-step; in flight during MFMA
            const float* tb2 = tb + (kk + 1) * BK;
            const float* sb2 = sb + (kk + 1) * BK;
#pragma unroll
            for (int j = 0; j < 8; ++j) {
                rA[j] = *reinterpret_cast<const float4*>(tb2 + (size_t)j * 16 * ND);
                rB[j] = *reinterpret_cast<const float4*>(sb2 + (size_t)j * 16 * ND);
            }
        }

#pragma unroll
        for (int ks = 0; ks < 2; ++ks) {
            short8 af[4], bf[4];
            const int kb = ks * 32 + lhi * 8;
#pragma unroll
            for (int m = 0; m < 4; ++m) {
                const int row = wr + m * 16 + llo;
                const int off = row * BK + (kb ^ ((row & 7) << 3));
                af[m] = *reinterpret_cast<const short8*>(&As[off]);
            }
#pragma unroll
            for (int n = 0; n < 4; ++n) {
                const int row = wc + n * 16 + llo;
                const int off = row * BK + (kb ^ ((row & 7) << 3));
                bf[n] = *reinterpret_cast<const short8*>(&Bs[off]);
            }
#pragma unroll
            for (int m = 0; m < 4; ++m)
#pragma unroll
                for (int n = 0; n < 4; ++n)
                    acc[m][n] = __builtin_amdgcn_mfma_f32_16x16x32_bf16(
                        af[m], bf[n], acc[m][n], 0, 0, 0);
        }
    }

    // reduce row sum-of-squares across the 16 staging threads of each row
    // (they are 16 contiguous, 16-aligned lanes -> xor<16 stays in-group)
#pragma unroll
    for (int d = 1; d < 16; d <<= 1) {
#pragma unroll
        for (int j = 0; j < 8; ++j) {
            sqA[j] += __shfl_xor(sqA[j], d);
            sqB[j] += __shfl_xor(sqB[j], d);
        }
    }
#pragma unroll
    for (int j = 0; j < 8; ++j) {
        if (c == j) { // static index per rule #20
            tn[j * 16 + g] = sqrtf(sqA[j]);
            sn[j * 16 + g] = sqrtf(sqB[j]);
        }
    }
    __syncthreads();

    float* outp = out + (size_t)b * NT * NS;
#pragma unroll
    for (int m = 0; m < 4; ++m) {
        const int lr0 = wr + m * 16 + lhi * 4;
#pragma unroll
        for (int n = 0; n < 4; ++n) {
            const int lc = wc + n * 16 + llo;
            const float snv = sn[lc];
            const int col = bs0 + lc;
#pragma unroll
            for (int j = 0; j < 4; ++j) {
                const float denom = fmaxf(tn[lr0 + j] * snv, 1e-10f);
                outp[(size_t)(bt0 + lr0 + j) * NS + col] =
                    acc[m][n][j] / denom * 0.5f + 0.5f;
            }
        }
    }
}

extern "C" void kernel_launch(void* const* d_in, const int* in_sizes, int n_in,
                              void* d_out, int out_size, void* d_ws, size_t ws_size,
                              hipStream_t stream) {
    const float* sup = (const float*)d_in[0]; // supports [32,512,1024]
    const float* tgt = (const float*)d_in[1]; // targets  [32,512,1024]
    float* out = (float*)d_out;               // [32,512,512] f32
    (void)in_sizes; (void)n_in; (void)out_size; (void)d_ws; (void)ws_size;
    dim3 grid(16, NBATCH, 1); // x: 4x4 output tiles, y: batch
    paircos_mfma<<<grid, 256, 0, stream>>>(sup, tgt, out);
}

// Round 2
// 70.082 us; speedup vs baseline: 1.0543x; 1.0543x over previous
//
#include <hip/hip_runtime.h>
#include <hip/hip_bf16.h>

typedef __attribute__((ext_vector_type(8))) short short8;
typedef __attribute__((ext_vector_type(4))) short short4b;
typedef __attribute__((ext_vector_type(4))) float f32x4;

#define NBATCH 32
#define NT 512
#define NS 512
#define ND 1024
#define BM 128
#define BN 128
#define BK 64
#define NKSTEP (ND / BK) /* 16 */

__device__ __forceinline__ short f2bf(float f) {
    union { __hip_bfloat16 h; short s; } u;
    u.h = __float2bfloat16(f);
    return u.s;
}

// 128x128 output tile, 512 threads = 8 waves (2x4), each wave 64x32 via 4x2
// fragments of v_mfma_f32_16x16x32_bf16. Double-buffered LDS (one barrier per
// K-step), depth-2 global->reg pipeline. f32 inputs are reg-staged, converted
// to bf16 into XOR-swizzled LDS; row sum-of-squares accumulated during
// staging (each element loaded exactly once per block -> norms are free).
__global__ __launch_bounds__(512, 4)
void paircos_mfma(const float* __restrict__ sup, const float* __restrict__ tgt,
                  float* __restrict__ out) {
    __shared__ __align__(16) short As[2][BM * BK]; // targets tiles
    __shared__ __align__(16) short Bs[2][BN * BK]; // supports tiles
    __shared__ float tn[BM];
    __shared__ float sn[BN];

    const int tid = threadIdx.x;
    const int b   = blockIdx.y;
    const int bt0 = (blockIdx.x >> 2) * BM;
    const int bs0 = (blockIdx.x & 3)  * BN;

    // staging: thread covers rows {j*32 + rb : j=0..3}, float4-col c
    const int c  = tid & 15;  // 0..15
    const int rb = tid >> 4;  // 0..31

    const float* tb = tgt + (size_t)b * NT * ND + (size_t)(bt0 + rb) * ND + c * 4;
    const float* sb = sup + (size_t)b * NS * ND + (size_t)(bs0 + rb) * ND + c * 4;

    const int wave = tid >> 6;
    const int lane = tid & 63;
    const int wr  = (wave >> 2) * 64;  // 0 or 64
    const int wc  = (wave & 3) * 32;   // 0,32,64,96
    const int lhi = lane >> 4;         // 0..3 (k-group)
    const int llo = lane & 15;         // row/col within fragment

    f32x4 acc[4][2];
#pragma unroll
    for (int m = 0; m < 4; ++m)
#pragma unroll
        for (int n = 0; n < 2; ++n)
            acc[m][n] = (f32x4){0.f, 0.f, 0.f, 0.f};

    float sqA[4] = {0.f, 0.f, 0.f, 0.f};
    float sqB[4] = {0.f, 0.f, 0.f, 0.f};

    float4 rA[4], rB[4];

#define LOADT(KK)                                                              \
    do {                                                                       \
        const float* tb2 = tb + (KK) * BK;                                     \
        const float* sb2 = sb + (KK) * BK;                                     \
        _Pragma("unroll") for (int j = 0; j < 4; ++j) {                        \
            rA[j] = *reinterpret_cast<const float4*>(tb2 + (size_t)j * 32 * ND); \
            rB[j] = *reinterpret_cast<const float4*>(sb2 + (size_t)j * 32 * ND); \
        }                                                                      \
    } while (0)

#define STORET(BUF)                                                            \
    do {                                                                       \
        short* dA = As[BUF];                                                   \
        short* dB = Bs[BUF];                                                   \
        _Pragma("unroll") for (int j = 0; j < 4; ++j) {                        \
            const int row = j * 32 + rb;                                       \
            const int off = row * BK + ((c * 4) ^ ((row & 7) << 3));           \
            float4 a = rA[j];                                                  \
            sqA[j] = fmaf(a.x, a.x, fmaf(a.y, a.y, fmaf(a.z, a.z, fmaf(a.w, a.w, sqA[j])))); \
            short4b va = { f2bf(a.x), f2bf(a.y), f2bf(a.z), f2bf(a.w) };       \
            *reinterpret_cast<short4b*>(&dA[off]) = va;                        \
            float4 bb = rB[j];                                                 \
            sqB[j] = fmaf(bb.x, bb.x, fmaf(bb.y, bb.y, fmaf(bb.z, bb.z, fmaf(bb.w, bb.w, sqB[j])))); \
            short4b vb = { f2bf(bb.x), f2bf(bb.y), f2bf(bb.z), f2bf(bb.w) };   \
            *reinterpret_cast<short4b*>(&dB[off]) = vb;                        \
        }                                                                      \
    } while (0)

    // prologue: tile 0 -> buf0; tile 1 in regs
    LOADT(0);
    STORET(0);
    LOADT(1);
    __syncthreads(); // buf0 visible

    for (int kk = 0; kk < NKSTEP; ++kk) {
        // write tile kk+1 (regs) into the buffer freed at last barrier
        if (kk + 1 < NKSTEP) STORET((kk + 1) & 1);
        // issue global loads for tile kk+2; land during this iter's MFMA
        if (kk + 2 < NKSTEP) LOADT(kk + 2);

        const short* sAs = As[kk & 1];
        const short* sBs = Bs[kk & 1];
#pragma unroll
        for (int ks = 0; ks < 2; ++ks) {
            short8 af[4], bf[2];
            const int kb = ks * 32 + lhi * 8;
#pragma unroll
            for (int m = 0; m < 4; ++m) {
                const int row = wr + m * 16 + llo;
                const int off = row * BK + (kb ^ ((row & 7) << 3));
                af[m] = *reinterpret_cast<const short8*>(&sAs[off]);
            }
#pragma unroll
            for (int n = 0; n < 2; ++n) {
                const int row = wc + n * 16 + llo;
                const int off = row * BK + (kb ^ ((row & 7) << 3));
                bf[n] = *reinterpret_cast<const short8*>(&sBs[off]);
            }
#pragma unroll
            for (int m = 0; m < 4; ++m)
#pragma unroll
                for (int n = 0; n < 2; ++n)
                    acc[m][n] = __builtin_amdgcn_mfma_f32_16x16x32_bf16(
                        af[m], bf[n], acc[m][n], 0, 0, 0);
        }
        __syncthreads(); // tile kk consumed by all; tile kk+1 writes visible
    }

    // reduce row sum-of-squares across the 16 staging threads of each row
    // (16 contiguous, 16-aligned lanes -> xor<16 stays in-group)
#pragma unroll
    for (int d = 1; d < 16; d <<= 1) {
#pragma unroll
        for (int j = 0; j < 4; ++j) {
            sqA[j] += __shfl_xor(sqA[j], d);
            sqB[j] += __shfl_xor(sqB[j], d);
        }
    }
    if (c == 0) {
#pragma unroll
        for (int j = 0; j < 4; ++j) { // static index per rule #20
            tn[j * 32 + rb] = sqrtf(sqA[j]);
            sn[j * 32 + rb] = sqrtf(sqB[j]);
        }
    }
    __syncthreads();

    float* outp = out + (size_t)b * NT * NS;
#pragma unroll
    for (int m = 0; m < 4; ++m) {
        const int lr0 = wr + m * 16 + lhi * 4;
#pragma unroll
        for (int n = 0; n < 2; ++n) {
            const int lc = wc + n * 16 + llo;
            const float snv = sn[lc];
            const int col = bs0 + lc;
#pragma unroll
            for (int j = 0; j < 4; ++j) {
                const float denom = fmaxf(tn[lr0 + j] * snv, 1e-10f);
                outp[(size_t)(bt0 + lr0 + j) * NS + col] =
                    acc[m][n][j] / denom * 0.5f + 0.5f;
            }
        }
    }
}

extern "C" void kernel_launch(void* const* d_in, const int* in_sizes, int n_in,
                              void* d_out, int out_size, void* d_ws, size_t ws_size,
                              hipStream_t stream) {
    const float* sup = (const float*)d_in[0]; // supports [32,512,1024]
    const float* tgt = (const float*)d_in[1]; // targets  [32,512,1024]
    float* out = (float*)d_out;               // [32,512,512] f32
    (void)in_sizes; (void)n_in; (void)out_size; (void)d_ws; (void)ws_size;
    dim3 grid(16, NBATCH, 1); // x: 4x4 output tiles, y: batch
    paircos_mfma<<<grid, 512, 0, stream>>>(sup, tgt, out);
}